// Round 11
// baseline (509.849 us; speedup 1.0000x reference)
//
#include <hip/hip_runtime.h>
#include <math.h>

typedef unsigned int uint;
typedef unsigned short ushort;

// Problem constants (reference: B=2, T=128, N=128, H=8, Dh=64, FEA=512)
#define FEA 512
#define NH 8
#define DH 64
#define BB 2
#define TT 128
#define NN 128
#define MTOT (BB*TT*NN)     // 32768 rows
#define SEG 16              // T / H
#define BETA 0.3f
#define LNEPS 1e-5f

typedef __attribute__((ext_vector_type(8))) _Float16 f16x8; // MFMA A/B frag (4 VGPRs)
typedef __attribute__((ext_vector_type(4))) float f32x4;    // MFMA C/D frag
typedef __attribute__((ext_vector_type(8))) short s16x8;    // 16B vector ld/st

static __device__ __forceinline__ ushort f2h(float x) {     // RTNE fp32->fp16
  _Float16 h = (_Float16)x;
  return __builtin_bit_cast(ushort, h);
}
static __device__ __forceinline__ float h2f(ushort u) {     // exact fp16->fp32
  return (float)__builtin_bit_cast(_Float16, u);
}

// ---------------------------------------------------------------------------
// xt = x + te -> fp16. 2 chunks/thread (control; unchanged).
// ---------------------------------------------------------------------------
__global__ __launch_bounds__(256) void add_h(const float* __restrict__ x,
                                             const float* __restrict__ te,
                                             ushort* __restrict__ xth) {
  const size_t half = (size_t)MTOT * FEA / 2;
  size_t i0 = ((size_t)blockIdx.x * 256 + threadIdx.x) * 8;
  size_t i1 = i0 + half;
  float4 a0 = *(const float4*)&x[i0];
  float4 a1 = *(const float4*)&x[i0 + 4];
  float4 c0 = *(const float4*)&x[i1];
  float4 c1 = *(const float4*)&x[i1 + 4];
  float4 b0 = *(const float4*)&te[i0];
  float4 b1 = *(const float4*)&te[i0 + 4];
  float4 d0 = *(const float4*)&te[i1];
  float4 d1 = *(const float4*)&te[i1 + 4];
  s16x8 o0, o1;
  o0[0]=(short)f2h(a0.x+b0.x); o0[1]=(short)f2h(a0.y+b0.y);
  o0[2]=(short)f2h(a0.z+b0.z); o0[3]=(short)f2h(a0.w+b0.w);
  o0[4]=(short)f2h(a1.x+b1.x); o0[5]=(short)f2h(a1.y+b1.y);
  o0[6]=(short)f2h(a1.z+b1.z); o0[7]=(short)f2h(a1.w+b1.w);
  o1[0]=(short)f2h(c0.x+d0.x); o1[1]=(short)f2h(c0.y+d0.y);
  o1[2]=(short)f2h(c0.z+d0.z); o1[3]=(short)f2h(c0.w+d0.w);
  o1[4]=(short)f2h(c1.x+d1.x); o1[5]=(short)f2h(c1.y+d1.y);
  o1[6]=(short)f2h(c1.z+d1.z); o1[7]=(short)f2h(c1.w+d1.w);
  *(s16x8*)&xth[i0] = o0;
  *(s16x8*)&xth[i1] = o1;
}

// ---------------------------------------------------------------------------
// Convert + transpose all 6 weights fp32 [k][n] -> fp16 WT [n][k].
// ---------------------------------------------------------------------------
struct W6 { const float* s[6]; };

__global__ __launch_bounds__(256) void wconv(W6 w, ushort* __restrict__ dst) {
  __shared__ float t[32][33];
  const float* W = w.s[blockIdx.z];
  ushort* WT = dst + (size_t)blockIdx.z * FEA * FEA;
  const int k0 = blockIdx.y * 32, n0 = blockIdx.x * 32;
  const int tx = threadIdx.x & 31, ty = threadIdx.x >> 5;   // 32 x 8
  #pragma unroll
  for (int i = 0; i < 4; ++i)
    t[ty + i * 8][tx] = W[(size_t)(k0 + ty + i * 8) * FEA + n0 + tx];
  __syncthreads();
  #pragma unroll
  for (int i = 0; i < 4; ++i)
    WT[(size_t)(n0 + ty + i * 8) * FEA + k0 + tx] = f2h(t[tx][ty + i * 8]);
}

// ---------------------------------------------------------------------------
// C[M,512](fp16) = A[M,512](fp16) @ WT^T + bias(f32), optional relu.
// 128x128 tile, BK=32, 4 waves 2x2, XCD-chunked swizzle (T1).
// B (weights) bypasses LDS — loaded global->VGPR (L2-hot, ~1.5 MB working
// set), double-buffered one K-step ahead. A stays on global_load_lds +
// swizzled LDS, depth-2 counted vmcnt. Halves LDS traffic (48->24 KB/iter)
// and the DMA queue. In-order vmcnt accounting: prologue [B0x4, A0x2, A1x2]
// -> vmcnt(2); per-iter issue [B(t+1)x4, A(t+2)x2], wait vmcnt(2) (A(t+2)
// stays in flight); vmcnt(0) at t=14.
// ---------------------------------------------------------------------------
struct GArgs {
  const ushort* wt[3];
  const float* bias[3];
  ushort* out[3];
};

template<int RELU, int NW, int NWG>
__global__ __launch_bounds__(256) void gemm_h(const ushort* __restrict__ A, GArgs p) {
  __shared__ ushort As[2][4096];
  const int tid = threadIdx.x;
  // XCD-chunked bijective swizzle (NWG % 8 == 0)
  constexpr int CPX = NWG / 8;
  constexpr int XS = (NW == 3) ? 12 : 4;          // works per m-tile (x-fastest)
  const int wl = (blockIdx.x & 7) * CPX + (blockIdx.x >> 3);
  const int xw = wl % XS;
  const int m0 = (wl / XS) * 128;
  const int wsel = (NW == 3) ? (xw >> 2) : 0;
  const int n0 = ((NW == 3) ? (xw & 3) : xw) * 128;
  const ushort* __restrict__ WT = p.wt[wsel];
  const float*  __restrict__ bias = p.bias[wsel];
  ushort* __restrict__ C = p.out[wsel];
  const int lane = tid & 63;
  const int wid = tid >> 6;
  const int wm = wid >> 1, wn = wid & 1;          // 2x2 wave grid (64x64 each)
  const int c = lane & 15, g = lane >> 4;         // frag row, k-group

  f32x4 acc[4][4] = {};                           // [m-frag][n-frag], D = C^T

  // A staging map: LDS slot i (16B) <- global (r = i>>2, kq = (i&3)^((r>>1)&3))
  int r_[2], kq_[2];
  #pragma unroll
  for (int cc = 0; cc < 2; ++cc) {
    int i = cc * 256 + tid;
    r_[cc] = i >> 2;
    kq_[cc] = (i & 3) ^ ((r_[cc] >> 1) & 3);
  }

  auto stage = [&](int buf, int k0) {             // A only: 2 loads/thread
    #pragma unroll
    for (int cc = 0; cc < 2; ++cc) {
      const ushort* ga = A + (size_t)(m0 + r_[cc]) * 512 + k0 + kq_[cc] * 8;
      __builtin_amdgcn_global_load_lds(
          (const __attribute__((address_space(1))) void*)ga,
          (__attribute__((address_space(3))) void*)&As[buf][(cc * 256 + tid) * 8], 16, 0, 0);
    }
  };

  f16x8 bsel[2][4];                               // B frags, dbuf by K-step parity
  const ushort* wbase = WT + (size_t)(n0 + wn * 64 + c) * 512 + g * 8;
  auto loadB = [&](int x, int k0) {               // 4 x global_load_dwordx4 (L2)
    #pragma unroll
    for (int s = 0; s < 4; ++s)
      bsel[x][s] = *(const f16x8*)&wbase[(size_t)s * 16 * 512 + k0];
  };

  // Prologue: B0 first, then A0, A1 -> vmcnt(2) completes B0+A0, A1 in flight.
  loadB(0, 0);
  stage(0, 0);
  stage(1, 32);
  __builtin_amdgcn_sched_barrier(0);
  asm volatile("s_waitcnt vmcnt(2)" ::: "memory");
  __builtin_amdgcn_sched_barrier(0);
  __builtin_amdgcn_s_barrier();

  #pragma unroll
  for (int t = 0; t < 16; ++t) {
    const int bi = t & 1;

    f16x8 af[4];
    #pragma unroll
    for (int s = 0; s < 4; ++s) {
      int ra = wm * 64 + s * 16 + c;
      int sa = ra * 4 + (g ^ ((ra >> 1) & 3));
      af[s] = *(const f16x8*)&As[bi][sa * 8];
    }
    if (t < 15) loadB((t + 1) & 1, (t + 1) * 32); // B prefetch (VGPR)
    __builtin_amdgcn_sched_barrier(0);            // pin loads before waits
    asm volatile("s_waitcnt lgkmcnt(0)" ::: "memory");
    __builtin_amdgcn_sched_barrier(0);
    __builtin_amdgcn_s_barrier();                 // all waves done with buf bi

    if (t < 14) stage(bi, (t + 2) * 32);          // overwrite dead A buffer

    #pragma unroll
    for (int i = 0; i < 4; ++i)
      #pragma unroll
      for (int j = 0; j < 4; ++j)
        acc[i][j] = __builtin_amdgcn_mfma_f32_16x16x32_f16(bsel[t & 1][j], af[i], acc[i][j], 0, 0, 0);

    if (t < 15) {
      // Need A(t+1) + B(t+1) done; A(t+2) (newest 2) may stay in flight.
      if (t < 14) { asm volatile("s_waitcnt vmcnt(2)" ::: "memory"); }
      else        { asm volatile("s_waitcnt vmcnt(0)" ::: "memory"); }
      __builtin_amdgcn_sched_barrier(0);
      __builtin_amdgcn_s_barrier();
    }
  }

  // Epilogue: lane (g,c) frag (i,j) holds C[m0+wm*64+i*16+c][n0+wn*64+j*16+g*4+reg]
  float4 bv4[4];
  #pragma unroll
  for (int j = 0; j < 4; ++j)
    bv4[j] = *(const float4*)&bias[n0 + wn * 64 + j * 16 + g * 4];
  #pragma unroll
  for (int i = 0; i < 4; ++i) {
    const size_t rb = (size_t)(m0 + wm * 64 + i * 16 + c) * 512;
    #pragma unroll
    for (int j = 0; j < 4; ++j) {
      const int nb = n0 + wn * 64 + j * 16 + g * 4;
      float o0 = acc[i][j][0] + bv4[j].x;
      float o1 = acc[i][j][1] + bv4[j].y;
      float o2 = acc[i][j][2] + bv4[j].z;
      float o3 = acc[i][j][3] + bv4[j].w;
      if (RELU) {
        o0 = fmaxf(o0, 0.f); o1 = fmaxf(o1, 0.f);
        o2 = fmaxf(o2, 0.f); o3 = fmaxf(o3, 0.f);
      }
      uint2 pk;
      pk.x = (uint)f2h(o0) | ((uint)f2h(o1) << 16);
      pk.y = (uint)f2h(o2) | ((uint)f2h(o3) << 16);
      *(uint2*)&C[rb + nb] = pk;
    }
  }
}

// ---------------------------------------------------------------------------
// MFMA attention (fp16). Unchanged (control; < 51 µs).
// ---------------------------------------------------------------------------
__global__ __launch_bounds__(256) void attn_mfma(const ushort* __restrict__ kp,
                                                 const ushort* __restrict__ vp,
                                                 ushort* __restrict__ qo) {
  __shared__ ushort Ks[8192];      // 128t x 64d, 16B slots: slot(t,gs)=t*8+(gs^(t&7))
  __shared__ ushort Vt[8192];      // V^T 64d x 128t: slot(d,ts)=d*16+(ts^(d&7)^(d>>3))
  __shared__ ushort Pb[4][1024];   // per-wave P [32q][32t]: slot(qr,ts)=qr*4+(ts^(qr&3))
  __shared__ float  Lb[4][32];     // per-wave 1/l

  const int bid = blockIdx.x;
  const int h = bid & 7;
  const int n = (bid >> 3) & 127;
  const int b = bid >> 10;
  const int tid = threadIdx.x;
  const int lane = tid & 63;
  const int w = tid >> 6;
  const int g = lane >> 4, c = lane & 15;
  const size_t tstride = (size_t)NN * FEA;
  const size_t base = ((size_t)b * TT * NN + n) * FEA + (size_t)h * DH;

  #pragma unroll
  for (int it = 0; it < 4; ++it) {
    int i = it * 256 + tid;
    int t = i >> 3;
    int gd = (i & 7) ^ (t & 7);
    const ushort* gk = kp + base + (size_t)t * tstride + gd * 8;
    __builtin_amdgcn_global_load_lds(
        (const __attribute__((address_space(1))) void*)gk,
        (__attribute__((address_space(3))) void*)&Ks[i * 8], 16, 0, 0);
  }
  #pragma unroll
  for (int it = 0; it < 4; ++it) {
    int j = it * 256 + tid;
    int t = j >> 3, d0 = (j & 7) * 8;
    s16x8 vv = *(const s16x8*)&vp[base + (size_t)t * tstride + d0];
    #pragma unroll
    for (int jj = 0; jj < 8; ++jj) {
      int d = d0 + jj;
      int slot = d * 16 + ((t >> 3) ^ (d & 7) ^ (d >> 3));
      Vt[slot * 8 + (t & 7)] = (ushort)vv[jj];
    }
  }
  const int qb = w * 32;
  f16x8 Qf[2][2];
  #pragma unroll
  for (int qt = 0; qt < 2; ++qt)
    #pragma unroll
    for (int kf = 0; kf < 2; ++kf)
      Qf[qt][kf] = *(const f16x8*)
          &qo[base + (size_t)(qb + qt * 16 + c) * tstride + kf * 32 + g * 8];
  __syncthreads();   // drains vmcnt (global_load_lds) + lgkm

  const int fs = h * SEG;
  const int fe = (h == NH - 1) ? TT : fs + SEG;

  f32x4 Oa[2][4];
  #pragma unroll
  for (int qt = 0; qt < 2; ++qt)
    #pragma unroll
    for (int dt = 0; dt < 4; ++dt)
      Oa[qt][dt] = (f32x4){0.f, 0.f, 0.f, 0.f};
  float lsum[2] = {0.f, 0.f};

  for (int ch = 0; ch <= w; ++ch) {
    const int tc = ch * 32;
    f32x4 sf[2][2];
    #pragma unroll
    for (int tt2 = 0; tt2 < 2; ++tt2) {
      f16x8 Kf[2];
      #pragma unroll
      for (int kf = 0; kf < 2; ++kf) {
        int t = tc + tt2 * 16 + c;                    // A-frag row = c
        int slot = t * 8 + ((kf * 4 + g) ^ (c & 7));  // t&7 == c&7
        Kf[kf] = *(const f16x8*)&Ks[slot * 8];
      }
      #pragma unroll
      for (int qt = 0; qt < 2; ++qt) {
        f32x4 s = (f32x4){0.f, 0.f, 0.f, 0.f};
        s = __builtin_amdgcn_mfma_f32_16x16x32_f16(Kf[0], Qf[qt][0], s, 0, 0, 0);
        s = __builtin_amdgcn_mfma_f32_16x16x32_f16(Kf[1], Qf[qt][1], s, 0, 0, 0);
        sf[tt2][qt] = s;
      }
    }
    #pragma unroll
    for (int tt2 = 0; tt2 < 2; ++tt2) {
      #pragma unroll
      for (int qt = 0; qt < 2; ++qt) {
        const int q = qb + qt * 16 + c;               // D col = q
        const int qr = qt * 16 + c;                   // P-buf row
        #pragma unroll
        for (int pr = 0; pr < 2; ++pr) {
          float pv[2];
          #pragma unroll
          for (int rr = 0; rr < 2; ++rr) {
            int reg = pr * 2 + rr;
            int t = tc + tt2 * 16 + g * 4 + reg;      // D row = t
            float mult = (t >= fs && t < fe) ? 0.125f : 0.125f * BETA;
            float p = __expf(sf[tt2][qt][reg] * mult);
            p = (t <= q) ? p : 0.f;
            pv[rr] = p;
            lsum[qt] += p;
          }
          uint pk = (uint)f2h(pv[0]) | ((uint)f2h(pv[1]) << 16);
          int tl = tt2 * 16 + g * 4 + pr * 2;
          int slot = qr * 4 + ((tl >> 3) ^ (qr & 3));
          *(uint*)&Pb[w][slot * 8 + (tl & 7)] = pk;
        }
      }
    }
    f16x8 Vf[4];
    #pragma unroll
    for (int dt = 0; dt < 4; ++dt) {
      int d = dt * 16 + c;                            // B-frag col = d
      int slot = d * 16 + ((((tc >> 3)) + g) ^ (d & 7) ^ (d >> 3));
      Vf[dt] = *(const f16x8*)&Vt[slot * 8];
    }
    #pragma unroll
    for (int qt = 0; qt < 2; ++qt) {
      int qr = qt * 16 + c;                           // A-frag row = q
      int slot = qr * 4 + (g ^ (qr & 3));
      f16x8 Pa = *(const f16x8*)&Pb[w][slot * 8];
      #pragma unroll
      for (int dt = 0; dt < 4; ++dt)
        Oa[qt][dt] = __builtin_amdgcn_mfma_f32_16x16x32_f16(Pa, Vf[dt], Oa[qt][dt], 0, 0, 0);
    }
  }

  #pragma unroll
  for (int qt = 0; qt < 2; ++qt) {
    lsum[qt] += __shfl_xor(lsum[qt], 16, 64);
    lsum[qt] += __shfl_xor(lsum[qt], 32, 64);
  }
  if (g == 0) {
    Lb[w][c]      = 1.0f / lsum[0];
    Lb[w][16 + c] = 1.0f / lsum[1];
  }
  #pragma unroll
  for (int qt = 0; qt < 2; ++qt) {
    f32x4 linv = *(const f32x4*)&Lb[w][qt * 16 + g * 4];
    #pragma unroll
    for (int dt = 0; dt < 4; ++dt) {
      #pragma unroll
      for (int reg = 0; reg < 4; ++reg) {
        int q = qb + qt * 16 + g * 4 + reg;           // D row = q
        qo[base + (size_t)q * tstride + dt * 16 + c] = f2h(Oa[qt][dt][reg] * linv[reg]);
      }
    }
  }
}

// ---------------------------------------------------------------------------
// y = LayerNorm(a + r) over last dim 512; one wave/row, 4 rows/block.
// ---------------------------------------------------------------------------
template<int AH, int RH, int OH>
__global__ __launch_bounds__(256) void ln_add(const void* __restrict__ a_,
                                              const void* __restrict__ r_,
                                              void* __restrict__ y_) {
  const int lane = threadIdx.x & 63;
  const int w = threadIdx.x >> 6;
  const size_t row = (size_t)blockIdx.x * 4 + w;
  const size_t off = row * FEA + (size_t)lane * 8;
  float ua[8], ur[8], u[8];
  if (AH) {
    s16x8 v = *(const s16x8*)&((const ushort*)a_)[off];
    #pragma unroll
    for (int j = 0; j < 8; ++j) ua[j] = h2f((ushort)v[j]);
  } else {
    float4 v0 = *(const float4*)&((const float*)a_)[off];
    float4 v1 = *(const float4*)&((const float*)a_)[off + 4];
    ua[0]=v0.x; ua[1]=v0.y; ua[2]=v0.z; ua[3]=v0.w;
    ua[4]=v1.x; ua[5]=v1.y; ua[6]=v1.z; ua[7]=v1.w;
  }
  if (RH) {
    s16x8 v = *(const s16x8*)&((const ushort*)r_)[off];
    #pragma unroll
    for (int j = 0; j < 8; ++j) ur[j] = h2f((ushort)v[j]);
  } else {
    float4 v0 = *(const float4*)&((const float*)r_)[off];
    float4 v1 = *(const float4*)&((const float*)r_)[off + 4];
    ur[0]=v0.x; ur[1]=v0.y; ur[2]=v0.z; ur[3]=v0.w;
    ur[4]=v1.x; ur[5]=v1.y; ur[6]=v1.z; ur[7]=v1.w;
  }
  float sum = 0.f, sq = 0.f;
  #pragma unroll
  for (int j = 0; j < 8; ++j) {
    u[j] = ua[j] + ur[j];
    sum += u[j];
    sq = fmaf(u[j], u[j], sq);
  }
  #pragma unroll
  for (int m = 1; m < 64; m <<= 1) {
    sum += __shfl_xor(sum, m, 64);
    sq  += __shfl_xor(sq,  m, 64);
  }
  const float mean = sum * (1.0f / FEA);
  const float var = sq * (1.0f / FEA) - mean * mean;
  const float rstd = rsqrtf(var + LNEPS);
  if (OH) {
    s16x8 o;
    #pragma unroll
    for (int j = 0; j < 8; ++j) o[j] = (short)f2h((u[j] - mean) * rstd);
    *(s16x8*)&((ushort*)y_)[off] = o;
  } else {
    float4 o0, o1;
    o0.x=(u[0]-mean)*rstd; o0.y=(u[1]-mean)*rstd; o0.z=(u[2]-mean)*rstd; o0.w=(u[3]-mean)*rstd;
    o1.x=(u[4]-mean)*rstd; o1.y=(u[5]-mean)*rstd; o1.z=(u[6]-mean)*rstd; o1.w=(u[7]-mean)*rstd;
    *(float4*)&((float*)y_)[off] = o0;
    *(float4*)&((float*)y_)[off + 4] = o1;
  }
}

// ---------------------------------------------------------------------------
// Orchestration. ws (131 MiB): B0..B3 fp16 buffers (32 MiB each) + WB (3 MiB).
//   B0: xt_h -> y (step 6)   B1: q -> attnout -> h2   B2: k -> out1   B3: v -> h
// ---------------------------------------------------------------------------
extern "C" void kernel_launch(void* const* d_in, const int* in_sizes, int n_in,
                              void* d_out, int out_size, void* d_ws, size_t ws_size,
                              hipStream_t stream) {
  const float* x  = (const float*)d_in[0];
  const float* te = (const float*)d_in[1];
  const float* bq = (const float*)d_in[3];
  const float* bk = (const float*)d_in[5];
  const float* bv = (const float*)d_in[7];
  const float* bo = (const float*)d_in[9];
  const float* b1 = (const float*)d_in[11];
  const float* b2 = (const float*)d_in[13];
  float* out = (float*)d_out;

  const size_t E = (size_t)MTOT * FEA;           // 16,777,216
  ushort* B0 = (ushort*)d_ws;
  ushort* B1 = B0 + E;
  ushort* B2 = B1 + E;
  ushort* B3 = B2 + E;
  ushort* WB = B3 + E;                           // 6 x 512 x 512
  const size_t WE = (size_t)FEA * FEA;

  // 1. xt = x + te -> fp16 (2 chunks/thread)
  add_h<<<E / 16 / 256, 256, 0, stream>>>(x, te, B0);
  // 2. weights -> fp16, transposed
  W6 w;
  w.s[0] = (const float*)d_in[2];  w.s[1] = (const float*)d_in[4];
  w.s[2] = (const float*)d_in[6];  w.s[3] = (const float*)d_in[8];
  w.s[4] = (const float*)d_in[10]; w.s[5] = (const float*)d_in[12];
  wconv<<<dim3(16, 16, 6), 256, 0, stream>>>(w, WB);
  // 3. fused q,k,v GEMM (1D grid 3072, XCD-chunked swizzle)
  GArgs gqkv;
  gqkv.wt[0] = WB;          gqkv.bias[0] = bq; gqkv.out[0] = B1;
  gqkv.wt[1] = WB + WE;     gqkv.bias[1] = bk; gqkv.out[1] = B2;
  gqkv.wt[2] = WB + 2 * WE; gqkv.bias[2] = bv; gqkv.out[2] = B3;
  gemm_h<0, 3, 3072><<<3072, 256, 0, stream>>>(B0, gqkv);
  // 4. attention (MFMA, in-place over q)
  attn_mfma<<<BB * NN * NH, 256, 0, stream>>>(B2, B3, B1);
  // 5. out1 = attn @ Wo + bo
  GArgs go = {};
  go.wt[0] = WB + 3 * WE; go.bias[0] = bo; go.out[0] = B2;
  gemm_h<0, 1, 1024><<<1024, 256, 0, stream>>>(B1, go);
  // 6. y = LN(out1 + xt) -> fp16, in-place over B0
  ln_add<1, 1, 1><<<MTOT / 4, 256, 0, stream>>>(B2, B0, B0);
  // 7. h = relu(y @ W1 + b1)
  GArgs g1 = {};
  g1.wt[0] = WB + 4 * WE; g1.bias[0] = b1; g1.out[0] = B3;
  gemm_h<1, 1, 1024><<<1024, 256, 0, stream>>>(B0, g1);
  // 8. h2 = h @ W2 + b2
  GArgs g2 = {};
  g2.wt[0] = WB + 5 * WE; g2.bias[0] = b2; g2.out[0] = B1;
  gemm_h<0, 1, 1024><<<1024, 256, 0, stream>>>(B3, g2);
  // 9. out = LN(h2 + y) -> fp32
  ln_add<1, 1, 0><<<MTOT / 4, 256, 0, stream>>>(B1, B0, out);
}